// Round 2
// baseline (601.229 us; speedup 1.0000x reference)
//
#include <hip/hip_runtime.h>

#define NY 512
#define NX 512
#define NSHOT 4
#define NSRC 2
#define NREC 64
#define NT 32
#define DTF 0.0005f
#define PML_W 20
#define C1F 1.125f
#define C2F (-1.0f/24.0f)
#define INV_DX 0.2f

// Padded per-shot field layout: [NYP][NXP] with interior at (2,2).
// Halo cells stay zero forever (compute writes interior only), so every
// stencil tap is an unconditional load: base-offset + compile-time imm.
#define NXP 516
#define NYP 516
#define FS (NYP*NXP)

// PML strips: sigma>0 only for index in [0,20) or [492,512). Outside, a==0
// so m = b*m stays 0 given zero init — skip m-field traffic entirely.
// Strip boundaries (20, 492) are EVEN, so a float2 pair never straddles them.
__device__ __forceinline__ bool in_pml(int i) {
    return (i < PML_W) | (i >= NY - PML_W);
}

__device__ __forceinline__ float2 ldf2(const float* __restrict__ p) {
    return *(const float2* __restrict__)p;
}
__device__ __forceinline__ void stf2(float* __restrict__ p, float a, float b) {
    *(float2*)p = make_float2(a, b);
}

__global__ void init_profiles(float* __restrict__ pa, float* __restrict__ pb) {
    int i = blockIdx.x * blockDim.x + threadIdx.x;
    if (i >= NY) return;
    float w = (float)PML_W;
    float x = (float)i;
    float frac = fmaxf((w - x) / w, (x - (float)(NY - 1 - PML_W)) / w);
    frac = fminf(fmaxf(frac, 0.0f), 1.0f);
    float sigma = 3.0f * 3500.0f * 6.9077553f / (2.0f * w * 5.0f) * frac * frac;
    float alpha = 78.539816f; // pi * 25
    float b = __expf(-(sigma + alpha) * DTF);
    pb[i] = b;
    pa[i] = sigma / (sigma + alpha) * (b - 1.0f);
}

// Zero the halo ring of the 5 stencil-read fields (vy,vx,syy,sxy,sxx).
// 5 fields x 4 shots x 4112 halo cells = 82240 writes (~330 KB), replaces
// the 54.5 MB full memset (FIRST-step kernels initialize the interiors).
__global__ void halo_zero(float* __restrict__ fields) {
    const int per = 4112;                 // 4*516 (top/bot rows) + 512*4 (side cols)
    int i = blockIdx.x * blockDim.x + threadIdx.x;
    if (i >= 5 * NSHOT * per) return;
    int f = i / (NSHOT * per);
    int r0 = i % (NSHOT * per);
    int sh = r0 / per;
    int h  = r0 % per;
    int row, col;
    if (h < 2064) {                        // rows {0,1,514,515}, all cols
        int r = h / NXP; col = h % NXP;
        row = (r < 2) ? r : 512 + r;
    } else {                               // cols {0,1,514,515}, rows 2..513
        int h2 = h - 2064;
        int cc = h2 & 3;
        row = 2 + (h2 >> 2);
        col = (cc < 2) ? cc : 512 + cc;
    }
    fields[(size_t)f * NSHOT * FS + (size_t)sh * FS + row * NXP + col] = 0.0f;
}

// XCD-aware bijective swizzle: 2048 blocks (one per (shot,row)), 2048%8==0.
// XCD k owns 256 consecutive (s,y) rows = half a shot -> L2-local stencil
// neighbors + vel<->stress producer/consumer reuse.
__device__ __forceinline__ void swz(int& s, int& y) {
    int flat = (int)blockIdx.x;
    int c = (flat & 7) * 256 + (flat >> 3);
    y = c & 511;
    s = c >> 9;
}

template<bool FIRST>
__global__ __launch_bounds__(256) void vel_kernel(
    const float* __restrict__ syy, const float* __restrict__ sxy, const float* __restrict__ sxx,
    float* __restrict__ vy, float* __restrict__ vx,
    float* __restrict__ m_syyy, float* __restrict__ m_sxyy,
    float* __restrict__ m_sxyx, float* __restrict__ m_sxxx,
    const float* __restrict__ buoy,
    const float* __restrict__ pa, const float* __restrict__ pb,
    const float* __restrict__ amps, const int* __restrict__ srcloc, int t)
{
    int s, y; swz(s, y);
    int x0 = (int)threadIdx.x * 2;
    int off = s * FS + (y + 2) * NXP + (x0 + 2);
    const float2 z2 = make_float2(0.0f, 0.0f);

    // dsyy = diff_minus(syy, y): C1*(f[y]-f[y-1]) + C2*(f[y+1]-f[y-2])
    float2 syy_m2 = FIRST ? z2 : ldf2(syy + off - 2 * NXP);
    float2 syy_m1 = FIRST ? z2 : ldf2(syy + off - NXP);
    float2 syy_0  = FIRST ? z2 : ldf2(syy + off);
    float2 syy_p1 = FIRST ? z2 : ldf2(syy + off + NXP);
    float dsyy_a = (C1F * (syy_0.x - syy_m1.x) + C2F * (syy_p1.x - syy_m2.x)) * INV_DX;
    float dsyy_b = (C1F * (syy_0.y - syy_m1.y) + C2F * (syy_p1.y - syy_m2.y)) * INV_DX;

    float2 sxy_ym1 = FIRST ? z2 : ldf2(sxy + off - NXP);
    float2 sxy_0   = FIRST ? z2 : ldf2(sxy + off);
    float2 sxy_yp1 = FIRST ? z2 : ldf2(sxy + off + NXP);
    float2 sxy_yp2 = FIRST ? z2 : ldf2(sxy + off + 2 * NXP);
    float2 sxy_xm2 = FIRST ? z2 : ldf2(sxy + off - 2);
    float2 sxy_xp2 = FIRST ? z2 : ldf2(sxy + off + 2);
    // dsxy_x = diff_plus(sxy, x): C1*(f[x+1]-f[x]) + C2*(f[x+2]-f[x-1])
    float dsxyx_a = (C1F * (sxy_0.y - sxy_0.x) + C2F * (sxy_xp2.x - sxy_xm2.y)) * INV_DX;
    float dsxyx_b = (C1F * (sxy_xp2.x - sxy_0.y) + C2F * (sxy_xp2.y - sxy_0.x)) * INV_DX;
    // dsxy_y = diff_plus(sxy, y)
    float dsxyy_a = (C1F * (sxy_yp1.x - sxy_0.x) + C2F * (sxy_yp2.x - sxy_ym1.x)) * INV_DX;
    float dsxyy_b = (C1F * (sxy_yp1.y - sxy_0.y) + C2F * (sxy_yp2.y - sxy_ym1.y)) * INV_DX;

    // dsxx = diff_minus(sxx, x)
    float2 sxx_xm2 = FIRST ? z2 : ldf2(sxx + off - 2);
    float2 sxx_0   = FIRST ? z2 : ldf2(sxx + off);
    float2 sxx_xp2 = FIRST ? z2 : ldf2(sxx + off + 2);
    float dsxx_a = (C1F * (sxx_0.x - sxx_xm2.y) + C2F * (sxx_0.y - sxx_xm2.x)) * INV_DX;
    float dsxx_b = (C1F * (sxx_0.y - sxx_0.x) + C2F * (sxx_xp2.x - sxx_xm2.y)) * INV_DX;

    float msyyy_a = 0.0f, msyyy_b = 0.0f, msxyy_a = 0.0f, msxyy_b = 0.0f;
    if (in_pml(y)) {   // wave-uniform (y uniform per block)
        float ay = pa[y], by = pb[y];
        float2 mo = FIRST ? z2 : ldf2(m_syyy + off);
        msyyy_a = by * mo.x + ay * dsyy_a;
        msyyy_b = by * mo.y + ay * dsyy_b;
        stf2(m_syyy + off, msyyy_a, msyyy_b);
        float2 mo2 = FIRST ? z2 : ldf2(m_sxyy + off);
        msxyy_a = by * mo2.x + ay * dsxyy_a;
        msxyy_b = by * mo2.y + ay * dsxyy_b;
        stf2(m_sxyy + off, msxyy_a, msxyy_b);
    }
    float msxyx_a = 0.0f, msxyx_b = 0.0f, msxxx_a = 0.0f, msxxx_b = 0.0f;
    if (in_pml(x0)) {  // pair-uniform (boundaries even)
        float2 ax = ldf2(pa + x0), bx = ldf2(pb + x0);
        float2 mo = FIRST ? z2 : ldf2(m_sxyx + off);
        msxyx_a = bx.x * mo.x + ax.x * dsxyx_a;
        msxyx_b = bx.y * mo.y + ax.y * dsxyx_b;
        stf2(m_sxyx + off, msxyx_a, msxyx_b);
        float2 mo2 = FIRST ? z2 : ldf2(m_sxxx + off);
        msxxx_a = bx.x * mo2.x + ax.x * dsxx_a;
        msxxx_b = bx.y * mo2.y + ax.y * dsxx_b;
        stf2(m_sxxx + off, msxxx_a, msxxx_b);
    }

    float2 bu  = ldf2(buoy + y * NX + x0);
    float2 vyo = FIRST ? z2 : ldf2(vy + off);
    float2 vxo = FIRST ? z2 : ldf2(vx + off);
    float vy_a = vyo.x + DTF * bu.x * ((dsyy_a + msyyy_a) + (dsxyx_a + msxyx_a));
    float vy_b = vyo.y + DTF * bu.y * ((dsyy_b + msyyy_b) + (dsxyx_b + msxyx_b));
    float vx_a = vxo.x + DTF * bu.x * ((dsxyy_a + msxyy_a) + (dsxx_a + msxxx_a));
    float vx_b = vxo.y + DTF * bu.y * ((dsxyy_b + msxyy_b) + (dsxx_b + msxxx_b));

#pragma unroll
    for (int i = 0; i < NSRC; ++i) {
        int sy = srcloc[(s * NSRC + i) * 2 + 0];
        int sx = srcloc[(s * NSRC + i) * 2 + 1];
        if (sy == y && (sx & ~1) == x0) {
            float amp = amps[(s * NSRC + i) * NT + t] * DTF;
            if (sx == x0) vy_a += amp * bu.x;
            else          vy_b += amp * bu.y;
        }
    }
    stf2(vy + off, vy_a, vy_b);
    stf2(vx + off, vx_a, vx_b);
}

template<bool FIRST>
__global__ __launch_bounds__(256) void stress_kernel(
    const float* __restrict__ vy, const float* __restrict__ vx,
    float* __restrict__ syy, float* __restrict__ sxy, float* __restrict__ sxx,
    float* __restrict__ m_vyy, float* __restrict__ m_vyx,
    float* __restrict__ m_vxy, float* __restrict__ m_vxx,
    const float* __restrict__ lamb, const float* __restrict__ mu,
    const float* __restrict__ pa, const float* __restrict__ pb,
    const int* __restrict__ recloc, float* __restrict__ out, int t)
{
    int s, y; swz(s, y);
    int x0 = (int)threadIdx.x * 2;
    int off = s * FS + (y + 2) * NXP + (x0 + 2);
    const float2 z2 = make_float2(0.0f, 0.0f);

    // receiver recording: vy is read-only here, updated by this step's vel.
    if (blockIdx.x == 0) {
        int p = threadIdx.x;
        if (p < NSHOT * NREC) {
            int sh = p / NREC;
            int ry = recloc[p * 2 + 0];
            int rx = recloc[p * 2 + 1];
            out[p * NT + t] = vy[sh * FS + (ry + 2) * NXP + (rx + 2)];
        }
    }

    float2 vy_ym1 = ldf2(vy + off - NXP);
    float2 vy_0   = ldf2(vy + off);
    float2 vy_yp1 = ldf2(vy + off + NXP);
    float2 vy_yp2 = ldf2(vy + off + 2 * NXP);
    float2 vy_xm2 = ldf2(vy + off - 2);
    float2 vy_xp2 = ldf2(vy + off + 2);
    // dvyy = diff_plus(vy, y)
    float dvyy_a = (C1F * (vy_yp1.x - vy_0.x) + C2F * (vy_yp2.x - vy_ym1.x)) * INV_DX;
    float dvyy_b = (C1F * (vy_yp1.y - vy_0.y) + C2F * (vy_yp2.y - vy_ym1.y)) * INV_DX;
    // dvyx = diff_minus(vy, x)
    float dvyx_a = (C1F * (vy_0.x - vy_xm2.y) + C2F * (vy_0.y - vy_xm2.x)) * INV_DX;
    float dvyx_b = (C1F * (vy_0.y - vy_0.x) + C2F * (vy_xp2.x - vy_xm2.y)) * INV_DX;

    float2 vx_ym2 = ldf2(vx + off - 2 * NXP);
    float2 vx_ym1 = ldf2(vx + off - NXP);
    float2 vx_0   = ldf2(vx + off);
    float2 vx_yp1 = ldf2(vx + off + NXP);
    float2 vx_xm2 = ldf2(vx + off - 2);
    float2 vx_xp2 = ldf2(vx + off + 2);
    // dvxx = diff_plus(vx, x)
    float dvxx_a = (C1F * (vx_0.y - vx_0.x) + C2F * (vx_xp2.x - vx_xm2.y)) * INV_DX;
    float dvxx_b = (C1F * (vx_xp2.x - vx_0.y) + C2F * (vx_xp2.y - vx_0.x)) * INV_DX;
    // dvxy = diff_minus(vx, y)
    float dvxy_a = (C1F * (vx_0.x - vx_ym1.x) + C2F * (vx_yp1.x - vx_ym2.x)) * INV_DX;
    float dvxy_b = (C1F * (vx_0.y - vx_ym1.y) + C2F * (vx_yp1.y - vx_ym2.y)) * INV_DX;

    float mvyy_a = 0.0f, mvyy_b = 0.0f, mvxy_a = 0.0f, mvxy_b = 0.0f;
    if (in_pml(y)) {
        float ay = pa[y], by = pb[y];
        float2 mo = FIRST ? z2 : ldf2(m_vyy + off);
        mvyy_a = by * mo.x + ay * dvyy_a;
        mvyy_b = by * mo.y + ay * dvyy_b;
        stf2(m_vyy + off, mvyy_a, mvyy_b);
        float2 mo2 = FIRST ? z2 : ldf2(m_vxy + off);
        mvxy_a = by * mo2.x + ay * dvxy_a;
        mvxy_b = by * mo2.y + ay * dvxy_b;
        stf2(m_vxy + off, mvxy_a, mvxy_b);
    }
    float mvxx_a = 0.0f, mvxx_b = 0.0f, mvyx_a = 0.0f, mvyx_b = 0.0f;
    if (in_pml(x0)) {
        float2 ax = ldf2(pa + x0), bx = ldf2(pb + x0);
        float2 mo = FIRST ? z2 : ldf2(m_vxx + off);
        mvxx_a = bx.x * mo.x + ax.x * dvxx_a;
        mvxx_b = bx.y * mo.y + ax.y * dvxx_b;
        stf2(m_vxx + off, mvxx_a, mvxx_b);
        float2 mo2 = FIRST ? z2 : ldf2(m_vyx + off);
        mvyx_a = bx.x * mo2.x + ax.x * dvyx_a;
        mvyx_b = bx.y * mo2.y + ax.y * dvyx_b;
        stf2(m_vyx + off, mvyx_a, mvyx_b);
    }

    float tvyy_a = dvyy_a + mvyy_a, tvyy_b = dvyy_b + mvyy_b;
    float tvxx_a = dvxx_a + mvxx_a, tvxx_b = dvxx_b + mvxx_b;
    float2 la  = ldf2(lamb + y * NX + x0);
    float2 muv = ldf2(mu + y * NX + x0);
    float l2m_a = la.x + 2.0f * muv.x, l2m_b = la.y + 2.0f * muv.y;
    float2 syyo = FIRST ? z2 : ldf2(syy + off);
    float2 sxxo = FIRST ? z2 : ldf2(sxx + off);
    float2 sxyo = FIRST ? z2 : ldf2(sxy + off);
    stf2(syy + off, syyo.x + DTF * (l2m_a * tvyy_a + la.x * tvxx_a),
                    syyo.y + DTF * (l2m_b * tvyy_b + la.y * tvxx_b));
    stf2(sxx + off, sxxo.x + DTF * (l2m_a * tvxx_a + la.x * tvyy_a),
                    sxxo.y + DTF * (l2m_b * tvxx_b + la.y * tvyy_b));
    stf2(sxy + off, sxyo.x + DTF * muv.x * ((dvyx_a + mvyx_a) + (dvxy_a + mvxy_a)),
                    sxyo.y + DTF * muv.y * ((dvyx_b + mvyx_b) + (dvxy_b + mvxy_b)));
}

extern "C" void kernel_launch(void* const* d_in, const int* in_sizes, int n_in,
                              void* d_out, int out_size, void* d_ws, size_t ws_size,
                              hipStream_t stream) {
    const float* lamb   = (const float*)d_in[0];
    const float* mu     = (const float*)d_in[1];
    const float* buoy   = (const float*)d_in[2];
    const float* amps   = (const float*)d_in[3];
    const int*   srcloc = (const int*)d_in[4];
    const int*   recloc = (const int*)d_in[5];
    float* out = (float*)d_out;

    float* ws = (float*)d_ws;
    float* pa = ws;
    float* pb = ws + 512;
    const size_t F = (size_t)NSHOT * FS;
    float* fields = ws + 1024;
    // stencil-read fields first (their halos get zeroed), then m-fields
    float* vy     = fields + 0  * F;
    float* vx     = fields + 1  * F;
    float* syy    = fields + 2  * F;
    float* sxy    = fields + 3  * F;
    float* sxx    = fields + 4  * F;
    float* m_vyy  = fields + 5  * F;
    float* m_vyx  = fields + 6  * F;
    float* m_vxy  = fields + 7  * F;
    float* m_vxx  = fields + 8  * F;
    float* m_syyy = fields + 9  * F;
    float* m_sxyy = fields + 10 * F;
    float* m_sxyx = fields + 11 * F;
    float* m_sxxx = fields + 12 * F;

    init_profiles<<<2, 256, 0, stream>>>(pa, pb);
    halo_zero<<<(5 * NSHOT * 4112 + 255) / 256, 256, 0, stream>>>(fields);

    dim3 grid(2048), block(256);
    vel_kernel<true><<<grid, block, 0, stream>>>(syy, sxy, sxx, vy, vx,
                                                 m_syyy, m_sxyy, m_sxyx, m_sxxx,
                                                 buoy, pa, pb, amps, srcloc, 0);
    stress_kernel<true><<<grid, block, 0, stream>>>(vy, vx, syy, sxy, sxx,
                                                    m_vyy, m_vyx, m_vxy, m_vxx,
                                                    lamb, mu, pa, pb, recloc, out, 0);
    for (int t = 1; t < NT; ++t) {
        vel_kernel<false><<<grid, block, 0, stream>>>(syy, sxy, sxx, vy, vx,
                                                      m_syyy, m_sxyy, m_sxyx, m_sxxx,
                                                      buoy, pa, pb, amps, srcloc, t);
        stress_kernel<false><<<grid, block, 0, stream>>>(vy, vx, syy, sxy, sxx,
                                                         m_vyy, m_vyx, m_vxy, m_vxx,
                                                         lamb, mu, pa, pb, recloc, out, t);
    }
}

// Round 3
// 492.881 us; speedup vs baseline: 1.2198x; 1.2198x over previous
//
#include <hip/hip_runtime.h>

#define NY 512
#define NX 512
#define NSHOT 4
#define NSRC 2
#define NREC 64
#define NT 32
#define DTF 0.0005f
#define PML_W 20
#define C1F 1.125f
#define C2F (-1.0f/24.0f)
#define INV_DX 0.2f

// x-padded layout: row stride 516, interior at x+2. x-halo cols {0,1,514,515}
// are zeroed once for the 5 stencil-read fields -> x taps are unconditional
// scalar loads (no per-lane bounds checks). y is NOT padded: y-taps use
// block-uniform guards (y is blockIdx-derived -> scalar branch, near free).
#define NXS 516
#define FSH (NY*NXS)

// PML strips: sigma>0 only for index in [0,20) or [492,512). Outside, a==0
// so m = b*m stays 0 given zero init — skip m-field traffic entirely.
__device__ __forceinline__ bool in_pml(int i) {
    return (i < PML_W) | (i >= NY - PML_W);
}

__global__ void init_profiles(float* __restrict__ pa, float* __restrict__ pb) {
    int i = blockIdx.x * blockDim.x + threadIdx.x;
    if (i >= NY) return;
    float w = (float)PML_W;
    float x = (float)i;
    float frac = fmaxf((w - x) / w, (x - (float)(NY - 1 - PML_W)) / w);
    frac = fminf(fmaxf(frac, 0.0f), 1.0f);
    float sigma = 3.0f * 3500.0f * 6.9077553f / (2.0f * w * 5.0f) * frac * frac;
    float alpha = 78.539816f; // pi * 25
    float b = __expf(-(sigma + alpha) * DTF);
    pb[i] = b;
    pa[i] = sigma / (sigma + alpha) * (b - 1.0f);
}

// Zero x-halo cols {0,1,514,515} of the 5 stencil-read fields (vy,vx,syy,
// sxy,sxx) for all shots/rows: 5*4*512*4 = 40960 writes (~160 KB), replacing
// the 54.5 MB full memset (FIRST-step kernels initialize interiors).
__global__ void halo_zero(float* __restrict__ fields) {
    int i = blockIdx.x * blockDim.x + threadIdx.x;
    if (i >= 5 * NSHOT * NY * 4) return;
    int c   = i & 3;
    int r   = i >> 2;          // (field*NSHOT+shot)*NY + row
    int row = r % NY;
    int fs  = r / NY;          // 0..19 = field*NSHOT + shot
    int col = (c < 2) ? c : 512 + c;
    fields[(size_t)fs * FSH + row * NXS + col] = 0.0f;
}

// XCD-aware bijective block swizzle (unchanged from the 514us round-1 kernel).
// Grid = (2,512,4) = 4096 blocks, 4096%8==0 -> bijective. XCD k owns a
// contiguous half-shot band so stencil neighbors + vel<->stress reuse stay
// in the XCD-local 4 MB L2.
__device__ __forceinline__ void swizzle_block(int& s, int& y, int& xb) {
    int flat = (int)blockIdx.x + 2 * ((int)blockIdx.y + 512 * (int)blockIdx.z);
    int xcd   = flat & 7;
    int local = flat >> 3;
    int c = xcd * 512 + local;
    xb = c & 1;
    y  = (c >> 1) & 511;
    s  = c >> 10;
}

template<bool FIRST>
__global__ __launch_bounds__(256) void vel_kernel(
    const float* __restrict__ syy, const float* __restrict__ sxy, const float* __restrict__ sxx,
    float* __restrict__ vy, float* __restrict__ vx,
    float* __restrict__ m_syyy, float* __restrict__ m_sxyy,
    float* __restrict__ m_sxyx, float* __restrict__ m_sxxx,
    const float* __restrict__ buoy,
    const float* __restrict__ pa, const float* __restrict__ pb,
    const float* __restrict__ amps, const int* __restrict__ srcloc, int t)
{
    int s, y, xb;
    swizzle_block(s, y, xb);
    int x = xb * 256 + (int)threadIdx.x;
    int sbase = s * FSH;
    int idx = sbase + y * NXS + x + 2;

    // block-uniform y-guards (scalar); FIRST folds everything to zero
    const bool gm2 = !FIRST && (y >= 2);
    const bool gm1 = !FIRST && (y >= 1);
    const bool gp1 = !FIRST && (y <= NY - 2);
    const bool gp2 = !FIRST && (y <= NY - 3);

    // dsyy = diff_minus(syy, y): C1*(f[y]-f[y-1]) + C2*(f[y+1]-f[y-2])
    float syy_0  = FIRST ? 0.0f : syy[idx];
    float syy_m1 = gm1 ? syy[idx - NXS] : 0.0f;
    float syy_m2 = gm2 ? syy[idx - 2 * NXS] : 0.0f;
    float syy_p1 = gp1 ? syy[idx + NXS] : 0.0f;
    float dsyy = (C1F * (syy_0 - syy_m1) + C2F * (syy_p1 - syy_m2)) * INV_DX;

    // dsxy_x = diff_plus(sxy, x): C1*(f[x+1]-f[x]) + C2*(f[x+2]-f[x-1])
    float sxy_0   = FIRST ? 0.0f : sxy[idx];
    float sxy_xm1 = FIRST ? 0.0f : sxy[idx - 1];
    float sxy_xp1 = FIRST ? 0.0f : sxy[idx + 1];
    float sxy_xp2 = FIRST ? 0.0f : sxy[idx + 2];
    float dsxy_x = (C1F * (sxy_xp1 - sxy_0) + C2F * (sxy_xp2 - sxy_xm1)) * INV_DX;

    // dsxy_y = diff_plus(sxy, y)
    float sxy_ym1 = gm1 ? sxy[idx - NXS] : 0.0f;
    float sxy_yp1 = gp1 ? sxy[idx + NXS] : 0.0f;
    float sxy_yp2 = gp2 ? sxy[idx + 2 * NXS] : 0.0f;
    float dsxy_y = (C1F * (sxy_yp1 - sxy_0) + C2F * (sxy_yp2 - sxy_ym1)) * INV_DX;

    // dsxx = diff_minus(sxx, x)
    float sxx_0   = FIRST ? 0.0f : sxx[idx];
    float sxx_xm1 = FIRST ? 0.0f : sxx[idx - 1];
    float sxx_xm2 = FIRST ? 0.0f : sxx[idx - 2];
    float sxx_xp1 = FIRST ? 0.0f : sxx[idx + 1];
    float dsxx = (C1F * (sxx_0 - sxx_xm1) + C2F * (sxx_xp1 - sxx_xm2)) * INV_DX;

    // y-direction PML memory fields (uniform branch)
    float msyyy = 0.0f, msxyy = 0.0f;
    if (in_pml(y)) {
        float ay = pa[y], by = pb[y];
        float mo1 = FIRST ? 0.0f : m_syyy[idx];
        float mo2 = FIRST ? 0.0f : m_sxyy[idx];
        msyyy = by * mo1 + ay * dsyy;   m_syyy[idx] = msyyy;
        msxyy = by * mo2 + ay * dsxy_y; m_sxyy[idx] = msxyy;
    }
    // x-direction PML memory fields (lane-masked; untouched lines skipped)
    float msxyx = 0.0f, msxxx = 0.0f;
    if (in_pml(x)) {
        float ax = pa[x], bx = pb[x];
        float mo1 = FIRST ? 0.0f : m_sxyx[idx];
        float mo2 = FIRST ? 0.0f : m_sxxx[idx];
        msxyx = bx * mo1 + ax * dsxy_x; m_sxyx[idx] = msxyx;
        msxxx = bx * mo2 + ax * dsxx;   m_sxxx[idx] = msxxx;
    }

    float b = buoy[y * NX + x];
    float vyo = FIRST ? 0.0f : vy[idx];
    float vxo = FIRST ? 0.0f : vx[idx];
    float vy_new = vyo + DTF * b * ((dsyy + msyyy) + (dsxy_x + msxyx));
    vx[idx] = vxo + DTF * b * ((dsxy_y + msxyy) + (dsxx + msxxx));

    // source injection (after velocity update, before stress pass reads vy)
#pragma unroll
    for (int i = 0; i < NSRC; ++i) {
        int sy = srcloc[(s * NSRC + i) * 2 + 0];
        int sx = srcloc[(s * NSRC + i) * 2 + 1];
        if (sy == y && sx == x) {
            vy_new += amps[(s * NSRC + i) * NT + t] * DTF * b;
        }
    }
    vy[idx] = vy_new;
}

template<bool FIRST>
__global__ __launch_bounds__(256) void stress_kernel(
    const float* __restrict__ vy, const float* __restrict__ vx,
    float* __restrict__ syy, float* __restrict__ sxy, float* __restrict__ sxx,
    float* __restrict__ m_vyy, float* __restrict__ m_vyx,
    float* __restrict__ m_vxy, float* __restrict__ m_vxx,
    const float* __restrict__ lamb, const float* __restrict__ mu,
    const float* __restrict__ pa, const float* __restrict__ pb,
    const int* __restrict__ recloc, float* __restrict__ out, int t)
{
    int s, y, xb;
    swizzle_block(s, y, xb);
    int x = xb * 256 + (int)threadIdx.x;
    int sbase = s * FSH;
    int idx = sbase + y * NXS + x + 2;

    // receiver recording: vy is read-only in this kernel. 256 = NSHOT*NREC.
    if (blockIdx.x == 0 && blockIdx.y == 0 && blockIdx.z == 0) {
        int p = threadIdx.x;
        if (p < NSHOT * NREC) {
            int sh = p / NREC;
            int ry = recloc[p * 2 + 0];
            int rx = recloc[p * 2 + 1];
            out[p * NT + t] = vy[sh * FSH + ry * NXS + rx + 2];
        }
    }

    // vy/vx were fully written by this step's vel kernel: loads are real
    // even at FIRST; only the y-guards (domain edge) apply.
    const bool gm2 = (y >= 2);
    const bool gm1 = (y >= 1);
    const bool gp1 = (y <= NY - 2);
    const bool gp2 = (y <= NY - 3);

    // dvyy = diff_plus(vy, y)
    float vy_0   = vy[idx];
    float vy_ym1 = gm1 ? vy[idx - NXS] : 0.0f;
    float vy_yp1 = gp1 ? vy[idx + NXS] : 0.0f;
    float vy_yp2 = gp2 ? vy[idx + 2 * NXS] : 0.0f;
    float dvyy = (C1F * (vy_yp1 - vy_0) + C2F * (vy_yp2 - vy_ym1)) * INV_DX;

    // dvxx = diff_plus(vx, x)
    float vx_0   = vx[idx];
    float vx_xm1 = vx[idx - 1];
    float vx_xp1 = vx[idx + 1];
    float vx_xp2 = vx[idx + 2];
    float dvxx = (C1F * (vx_xp1 - vx_0) + C2F * (vx_xp2 - vx_xm1)) * INV_DX;

    // dvyx = diff_minus(vy, x)
    float vy_xm1 = vy[idx - 1];
    float vy_xm2 = vy[idx - 2];
    float vy_xp1 = vy[idx + 1];
    float dvyx = (C1F * (vy_0 - vy_xm1) + C2F * (vy_xp1 - vy_xm2)) * INV_DX;

    // dvxy = diff_minus(vx, y)
    float vx_ym1 = gm1 ? vx[idx - NXS] : 0.0f;
    float vx_ym2 = gm2 ? vx[idx - 2 * NXS] : 0.0f;
    float vx_yp1 = gp1 ? vx[idx + NXS] : 0.0f;
    float dvxy = (C1F * (vx_0 - vx_ym1) + C2F * (vx_yp1 - vx_ym2)) * INV_DX;

    // y-direction PML memory fields (uniform branch)
    float mvyy = 0.0f, mvxy = 0.0f;
    if (in_pml(y)) {
        float ay = pa[y], by = pb[y];
        float mo1 = FIRST ? 0.0f : m_vyy[idx];
        float mo2 = FIRST ? 0.0f : m_vxy[idx];
        mvyy = by * mo1 + ay * dvyy; m_vyy[idx] = mvyy;
        mvxy = by * mo2 + ay * dvxy; m_vxy[idx] = mvxy;
    }
    // x-direction PML memory fields (lane-masked)
    float mvxx = 0.0f, mvyx = 0.0f;
    if (in_pml(x)) {
        float ax = pa[x], bx = pb[x];
        float mo1 = FIRST ? 0.0f : m_vxx[idx];
        float mo2 = FIRST ? 0.0f : m_vyx[idx];
        mvxx = bx * mo1 + ax * dvxx; m_vxx[idx] = mvxx;
        mvyx = bx * mo2 + ax * dvyx; m_vyx[idx] = mvyx;
    }

    float tvyy = dvyy + mvyy;
    float tvxx = dvxx + mvxx;

    float la = lamb[y * NX + x];
    float m  = mu[y * NX + x];
    float l2m = la + 2.0f * m;
    float syyo = FIRST ? 0.0f : syy[idx];
    float sxxo = FIRST ? 0.0f : sxx[idx];
    float sxyo = FIRST ? 0.0f : sxy[idx];
    syy[idx] = syyo + DTF * (l2m * tvyy + la * tvxx);
    sxx[idx] = sxxo + DTF * (l2m * tvxx + la * tvyy);
    sxy[idx] = sxyo + DTF * m * ((dvyx + mvyx) + (dvxy + mvxy));
}

extern "C" void kernel_launch(void* const* d_in, const int* in_sizes, int n_in,
                              void* d_out, int out_size, void* d_ws, size_t ws_size,
                              hipStream_t stream) {
    const float* lamb   = (const float*)d_in[0];
    const float* mu     = (const float*)d_in[1];
    const float* buoy   = (const float*)d_in[2];
    const float* amps   = (const float*)d_in[3];
    const int*   srcloc = (const int*)d_in[4];
    const int*   recloc = (const int*)d_in[5];
    float* out = (float*)d_out;

    float* ws = (float*)d_ws;
    float* pa = ws;
    float* pb = ws + 512;
    const size_t F = (size_t)NSHOT * FSH;
    float* fields = ws + 1024;
    // stencil-read fields first (their x-halos get zeroed), then m-fields
    float* vy     = fields + 0  * F;
    float* vx     = fields + 1  * F;
    float* syy    = fields + 2  * F;
    float* sxy    = fields + 3  * F;
    float* sxx    = fields + 4  * F;
    float* m_vyy  = fields + 5  * F;
    float* m_vyx  = fields + 6  * F;
    float* m_vxy  = fields + 7  * F;
    float* m_vxx  = fields + 8  * F;
    float* m_syyy = fields + 9  * F;
    float* m_sxyy = fields + 10 * F;
    float* m_sxyx = fields + 11 * F;
    float* m_sxxx = fields + 12 * F;

    init_profiles<<<2, 256, 0, stream>>>(pa, pb);
    halo_zero<<<(5 * NSHOT * NY * 4 + 255) / 256, 256, 0, stream>>>(fields);

    dim3 grid(NX / 256, NY, NSHOT);
    dim3 block(256);
    vel_kernel<true><<<grid, block, 0, stream>>>(syy, sxy, sxx, vy, vx,
                                                 m_syyy, m_sxyy, m_sxyx, m_sxxx,
                                                 buoy, pa, pb, amps, srcloc, 0);
    stress_kernel<true><<<grid, block, 0, stream>>>(vy, vx, syy, sxy, sxx,
                                                    m_vyy, m_vyx, m_vxy, m_vxx,
                                                    lamb, mu, pa, pb, recloc, out, 0);
    for (int t = 1; t < NT; ++t) {
        vel_kernel<false><<<grid, block, 0, stream>>>(syy, sxy, sxx, vy, vx,
                                                      m_syyy, m_sxyy, m_sxyx, m_sxxx,
                                                      buoy, pa, pb, amps, srcloc, t);
        stress_kernel<false><<<grid, block, 0, stream>>>(vy, vx, syy, sxy, sxx,
                                                         m_vyy, m_vyx, m_vxy, m_vxx,
                                                         lamb, mu, pa, pb, recloc, out, t);
    }
}

// Round 4
// 490.633 us; speedup vs baseline: 1.2254x; 1.0046x over previous
//
#include <hip/hip_runtime.h>
#include <hip/hip_cooperative_groups.h>

namespace cg = cooperative_groups;

#define NY 512
#define NX 512
#define NSHOT 4
#define NSRC 2
#define NREC 64
#define NT 32
#define DTF 0.0005f
#define PML_W 20
#define C1F 1.125f
#define C2F (-1.0f/24.0f)
#define INV_DX 0.2f

// x-padded layout: row stride 516, interior at x+2. x-halo cols {0,1,514,515}
// zeroed once for the 5 stencil-read fields -> x taps unconditional.
#define NXS 516
#define FSH (NY*NXS)

__device__ __forceinline__ bool in_pml(int i) {
    return (i < PML_W) | (i >= NY - PML_W);
}

__global__ void init_profiles(float* __restrict__ pa, float* __restrict__ pb) {
    int i = blockIdx.x * blockDim.x + threadIdx.x;
    if (i >= NY) return;
    float w = (float)PML_W;
    float x = (float)i;
    float frac = fmaxf((w - x) / w, (x - (float)(NY - 1 - PML_W)) / w);
    frac = fminf(fmaxf(frac, 0.0f), 1.0f);
    float sigma = 3.0f * 3500.0f * 6.9077553f / (2.0f * w * 5.0f) * frac * frac;
    float alpha = 78.539816f; // pi * 25
    float b = __expf(-(sigma + alpha) * DTF);
    pb[i] = b;
    pa[i] = sigma / (sigma + alpha) * (b - 1.0f);
}

// Zero x-halo cols {0,1,514,515} of the 5 stencil-read fields.
__global__ void halo_zero(float* __restrict__ fields) {
    int i = blockIdx.x * blockDim.x + threadIdx.x;
    if (i >= 5 * NSHOT * NY * 4) return;
    int c   = i & 3;
    int r   = i >> 2;
    int row = r % NY;
    int fs  = r / NY;
    int col = (c < 2) ? c : 512 + c;
    fields[(size_t)fs * FSH + row * NXS + col] = 0.0f;
}

// ---------------- shared per-point physics (verbatim round-3 bodies) --------

template<bool FIRST>
__device__ __forceinline__ void vel_point(
    const float* __restrict__ syy, const float* __restrict__ sxy, const float* __restrict__ sxx,
    float* __restrict__ vy, float* __restrict__ vx,
    float* __restrict__ m_syyy, float* __restrict__ m_sxyy,
    float* __restrict__ m_sxyx, float* __restrict__ m_sxxx,
    const float* __restrict__ buoy,
    const float* __restrict__ pa, const float* __restrict__ pb,
    const float* __restrict__ amps, const int* __restrict__ srcloc,
    int t, int s, int y, int x)
{
    int idx = s * FSH + y * NXS + x + 2;

    const bool gm2 = !FIRST && (y >= 2);
    const bool gm1 = !FIRST && (y >= 1);
    const bool gp1 = !FIRST && (y <= NY - 2);
    const bool gp2 = !FIRST && (y <= NY - 3);

    // dsyy = diff_minus(syy, y)
    float syy_0  = FIRST ? 0.0f : syy[idx];
    float syy_m1 = gm1 ? syy[idx - NXS] : 0.0f;
    float syy_m2 = gm2 ? syy[idx - 2 * NXS] : 0.0f;
    float syy_p1 = gp1 ? syy[idx + NXS] : 0.0f;
    float dsyy = (C1F * (syy_0 - syy_m1) + C2F * (syy_p1 - syy_m2)) * INV_DX;

    // dsxy_x = diff_plus(sxy, x)
    float sxy_0   = FIRST ? 0.0f : sxy[idx];
    float sxy_xm1 = FIRST ? 0.0f : sxy[idx - 1];
    float sxy_xp1 = FIRST ? 0.0f : sxy[idx + 1];
    float sxy_xp2 = FIRST ? 0.0f : sxy[idx + 2];
    float dsxy_x = (C1F * (sxy_xp1 - sxy_0) + C2F * (sxy_xp2 - sxy_xm1)) * INV_DX;

    // dsxy_y = diff_plus(sxy, y)
    float sxy_ym1 = gm1 ? sxy[idx - NXS] : 0.0f;
    float sxy_yp1 = gp1 ? sxy[idx + NXS] : 0.0f;
    float sxy_yp2 = gp2 ? sxy[idx + 2 * NXS] : 0.0f;
    float dsxy_y = (C1F * (sxy_yp1 - sxy_0) + C2F * (sxy_yp2 - sxy_ym1)) * INV_DX;

    // dsxx = diff_minus(sxx, x)
    float sxx_0   = FIRST ? 0.0f : sxx[idx];
    float sxx_xm1 = FIRST ? 0.0f : sxx[idx - 1];
    float sxx_xm2 = FIRST ? 0.0f : sxx[idx - 2];
    float sxx_xp1 = FIRST ? 0.0f : sxx[idx + 1];
    float dsxx = (C1F * (sxx_0 - sxx_xm1) + C2F * (sxx_xp1 - sxx_xm2)) * INV_DX;

    float msyyy = 0.0f, msxyy = 0.0f;
    if (in_pml(y)) {
        float ay = pa[y], by = pb[y];
        float mo1 = FIRST ? 0.0f : m_syyy[idx];
        float mo2 = FIRST ? 0.0f : m_sxyy[idx];
        msyyy = by * mo1 + ay * dsyy;   m_syyy[idx] = msyyy;
        msxyy = by * mo2 + ay * dsxy_y; m_sxyy[idx] = msxyy;
    }
    float msxyx = 0.0f, msxxx = 0.0f;
    if (in_pml(x)) {
        float ax = pa[x], bx = pb[x];
        float mo1 = FIRST ? 0.0f : m_sxyx[idx];
        float mo2 = FIRST ? 0.0f : m_sxxx[idx];
        msxyx = bx * mo1 + ax * dsxy_x; m_sxyx[idx] = msxyx;
        msxxx = bx * mo2 + ax * dsxx;   m_sxxx[idx] = msxxx;
    }

    float b = buoy[y * NX + x];
    float vyo = FIRST ? 0.0f : vy[idx];
    float vxo = FIRST ? 0.0f : vx[idx];
    float vy_new = vyo + DTF * b * ((dsyy + msyyy) + (dsxy_x + msxyx));
    vx[idx] = vxo + DTF * b * ((dsxy_y + msxyy) + (dsxx + msxxx));

#pragma unroll
    for (int i = 0; i < NSRC; ++i) {
        int sy = srcloc[(s * NSRC + i) * 2 + 0];
        int sx = srcloc[(s * NSRC + i) * 2 + 1];
        if (sy == y && sx == x) {
            vy_new += amps[(s * NSRC + i) * NT + t] * DTF * b;
        }
    }
    vy[idx] = vy_new;
}

template<bool FIRST>
__device__ __forceinline__ void stress_point(
    const float* __restrict__ vy, const float* __restrict__ vx,
    float* __restrict__ syy, float* __restrict__ sxy, float* __restrict__ sxx,
    float* __restrict__ m_vyy, float* __restrict__ m_vyx,
    float* __restrict__ m_vxy, float* __restrict__ m_vxx,
    const float* __restrict__ lamb, const float* __restrict__ mu,
    const float* __restrict__ pa, const float* __restrict__ pb,
    int s, int y, int x)
{
    int idx = s * FSH + y * NXS + x + 2;

    const bool gm2 = (y >= 2);
    const bool gm1 = (y >= 1);
    const bool gp1 = (y <= NY - 2);
    const bool gp2 = (y <= NY - 3);

    // dvyy = diff_plus(vy, y)
    float vy_0   = vy[idx];
    float vy_ym1 = gm1 ? vy[idx - NXS] : 0.0f;
    float vy_yp1 = gp1 ? vy[idx + NXS] : 0.0f;
    float vy_yp2 = gp2 ? vy[idx + 2 * NXS] : 0.0f;
    float dvyy = (C1F * (vy_yp1 - vy_0) + C2F * (vy_yp2 - vy_ym1)) * INV_DX;

    // dvxx = diff_plus(vx, x)
    float vx_0   = vx[idx];
    float vx_xm1 = vx[idx - 1];
    float vx_xp1 = vx[idx + 1];
    float vx_xp2 = vx[idx + 2];
    float dvxx = (C1F * (vx_xp1 - vx_0) + C2F * (vx_xp2 - vx_xm1)) * INV_DX;

    // dvyx = diff_minus(vy, x)
    float vy_xm1 = vy[idx - 1];
    float vy_xm2 = vy[idx - 2];
    float vy_xp1 = vy[idx + 1];
    float dvyx = (C1F * (vy_0 - vy_xm1) + C2F * (vy_xp1 - vy_xm2)) * INV_DX;

    // dvxy = diff_minus(vx, y)
    float vx_ym1 = gm1 ? vx[idx - NXS] : 0.0f;
    float vx_ym2 = gm2 ? vx[idx - 2 * NXS] : 0.0f;
    float vx_yp1 = gp1 ? vx[idx + NXS] : 0.0f;
    float dvxy = (C1F * (vx_0 - vx_ym1) + C2F * (vx_yp1 - vx_ym2)) * INV_DX;

    float mvyy = 0.0f, mvxy = 0.0f;
    if (in_pml(y)) {
        float ay = pa[y], by = pb[y];
        float mo1 = FIRST ? 0.0f : m_vyy[idx];
        float mo2 = FIRST ? 0.0f : m_vxy[idx];
        mvyy = by * mo1 + ay * dvyy; m_vyy[idx] = mvyy;
        mvxy = by * mo2 + ay * dvxy; m_vxy[idx] = mvxy;
    }
    float mvxx = 0.0f, mvyx = 0.0f;
    if (in_pml(x)) {
        float ax = pa[x], bx = pb[x];
        float mo1 = FIRST ? 0.0f : m_vxx[idx];
        float mo2 = FIRST ? 0.0f : m_vyx[idx];
        mvxx = bx * mo1 + ax * dvxx; m_vxx[idx] = mvxx;
        mvyx = bx * mo2 + ax * dvyx; m_vyx[idx] = mvyx;
    }

    float tvyy = dvyy + mvyy;
    float tvxx = dvxx + mvxx;

    float la = lamb[y * NX + x];
    float m  = mu[y * NX + x];
    float l2m = la + 2.0f * m;
    float syyo = FIRST ? 0.0f : syy[idx];
    float sxxo = FIRST ? 0.0f : sxx[idx];
    float sxyo = FIRST ? 0.0f : sxy[idx];
    syy[idx] = syyo + DTF * (l2m * tvyy + la * tvxx);
    sxx[idx] = sxxo + DTF * (l2m * tvxx + la * tvyy);
    sxy[idx] = sxyo + DTF * m * ((dvyx + mvyx) + (dvxy + mvxy));
}

// ---------------- persistent cooperative kernel -----------------------------
// 1024 blocks x 256 threads, 4 blocks/CU resident (launch_bounds caps VGPR at
// 128). Block b handles units c = (b&7)*512 + (b>>3)*4 + k, k=0..3, where
// unit c -> (s = c>>10, y = (c>>1)&511, x-half = c&1): XCD (b&7) owns a
// contiguous half-shot band; each block does 2 consecutive rows, both halves.
// grid.sync() replaces the kernel-launch boundary between vel and stress.
__global__ __launch_bounds__(256, 4) void sim_kernel(
    float* __restrict__ vy, float* __restrict__ vx,
    float* __restrict__ syy, float* __restrict__ sxy, float* __restrict__ sxx,
    float* __restrict__ m_syyy, float* __restrict__ m_sxyy,
    float* __restrict__ m_sxyx, float* __restrict__ m_sxxx,
    float* __restrict__ m_vyy, float* __restrict__ m_vyx,
    float* __restrict__ m_vxy, float* __restrict__ m_vxx,
    const float* __restrict__ buoy, const float* __restrict__ lamb,
    const float* __restrict__ mu,
    const float* __restrict__ pa, const float* __restrict__ pb,
    const float* __restrict__ amps, const int* __restrict__ srcloc,
    const int* __restrict__ recloc, float* __restrict__ out)
{
    cg::grid_group grid = cg::this_grid();
    const int b    = (int)blockIdx.x;
    const int base = (b & 7) * 512 + (b >> 3) * 4;
    const int tid  = (int)threadIdx.x;

    for (int t = 0; t < NT; ++t) {
        if (t == 0) {
            for (int k = 0; k < 4; ++k) {
                int c = base + k;
                vel_point<true>(syy, sxy, sxx, vy, vx, m_syyy, m_sxyy, m_sxyx, m_sxxx,
                                buoy, pa, pb, amps, srcloc, t,
                                c >> 10, (c >> 1) & 511, (c & 1) * 256 + tid);
            }
        } else {
            for (int k = 0; k < 4; ++k) {
                int c = base + k;
                vel_point<false>(syy, sxy, sxx, vy, vx, m_syyy, m_sxyy, m_sxyx, m_sxxx,
                                 buoy, pa, pb, amps, srcloc, t,
                                 c >> 10, (c >> 1) & 511, (c & 1) * 256 + tid);
            }
        }
        grid.sync();   // vel(t) complete everywhere

        // receiver recording for step t (vy read-only until next vel phase;
        // ordered before next vel by the stress-end sync below)
        if (b == 0 && tid < NSHOT * NREC) {
            int sh = tid / NREC;
            int ry = recloc[tid * 2 + 0];
            int rx = recloc[tid * 2 + 1];
            out[tid * NT + t] = vy[sh * FSH + ry * NXS + rx + 2];
        }

        if (t == 0) {
            for (int k = 0; k < 4; ++k) {
                int c = base + k;
                stress_point<true>(vy, vx, syy, sxy, sxx, m_vyy, m_vyx, m_vxy, m_vxx,
                                   lamb, mu, pa, pb,
                                   c >> 10, (c >> 1) & 511, (c & 1) * 256 + tid);
            }
        } else {
            for (int k = 0; k < 4; ++k) {
                int c = base + k;
                stress_point<false>(vy, vx, syy, sxy, sxx, m_vyy, m_vyx, m_vxy, m_vxx,
                                    lamb, mu, pa, pb,
                                    c >> 10, (c >> 1) & 511, (c & 1) * 256 + tid);
            }
        }
        grid.sync();   // stress(t) + rec(t) complete everywhere
    }
}

// ---------------- fallback multi-launch kernels (verified round-3 path) -----

__device__ __forceinline__ void swizzle_block(int& s, int& y, int& xb) {
    int flat = (int)blockIdx.x + 2 * ((int)blockIdx.y + 512 * (int)blockIdx.z);
    int xcd   = flat & 7;
    int local = flat >> 3;
    int c = xcd * 512 + local;
    xb = c & 1;
    y  = (c >> 1) & 511;
    s  = c >> 10;
}

template<bool FIRST>
__global__ __launch_bounds__(256) void vel_kernel(
    const float* __restrict__ syy, const float* __restrict__ sxy, const float* __restrict__ sxx,
    float* __restrict__ vy, float* __restrict__ vx,
    float* __restrict__ m_syyy, float* __restrict__ m_sxyy,
    float* __restrict__ m_sxyx, float* __restrict__ m_sxxx,
    const float* __restrict__ buoy,
    const float* __restrict__ pa, const float* __restrict__ pb,
    const float* __restrict__ amps, const int* __restrict__ srcloc, int t)
{
    int s, y, xb;
    swizzle_block(s, y, xb);
    vel_point<FIRST>(syy, sxy, sxx, vy, vx, m_syyy, m_sxyy, m_sxyx, m_sxxx,
                     buoy, pa, pb, amps, srcloc, t, s, y, xb * 256 + (int)threadIdx.x);
}

template<bool FIRST>
__global__ __launch_bounds__(256) void stress_kernel(
    const float* __restrict__ vy, const float* __restrict__ vx,
    float* __restrict__ syy, float* __restrict__ sxy, float* __restrict__ sxx,
    float* __restrict__ m_vyy, float* __restrict__ m_vyx,
    float* __restrict__ m_vxy, float* __restrict__ m_vxx,
    const float* __restrict__ lamb, const float* __restrict__ mu,
    const float* __restrict__ pa, const float* __restrict__ pb,
    const int* __restrict__ recloc, float* __restrict__ out, int t)
{
    int s, y, xb;
    swizzle_block(s, y, xb);
    if (blockIdx.x == 0 && blockIdx.y == 0 && blockIdx.z == 0) {
        int p = threadIdx.x;
        if (p < NSHOT * NREC) {
            int sh = p / NREC;
            int ry = recloc[p * 2 + 0];
            int rx = recloc[p * 2 + 1];
            out[p * NT + t] = vy[sh * FSH + ry * NXS + rx + 2];
        }
    }
    stress_point<FIRST>(vy, vx, syy, sxy, sxx, m_vyy, m_vyx, m_vxy, m_vxx,
                        lamb, mu, pa, pb, s, y, xb * 256 + (int)threadIdx.x);
}

extern "C" void kernel_launch(void* const* d_in, const int* in_sizes, int n_in,
                              void* d_out, int out_size, void* d_ws, size_t ws_size,
                              hipStream_t stream) {
    const float* lamb   = (const float*)d_in[0];
    const float* mu     = (const float*)d_in[1];
    const float* buoy   = (const float*)d_in[2];
    const float* amps   = (const float*)d_in[3];
    const int*   srcloc = (const int*)d_in[4];
    const int*   recloc = (const int*)d_in[5];
    float* out = (float*)d_out;

    float* ws = (float*)d_ws;
    float* pa = ws;
    float* pb = ws + 512;
    const size_t F = (size_t)NSHOT * FSH;
    float* fields = ws + 1024;
    float* vy     = fields + 0  * F;
    float* vx     = fields + 1  * F;
    float* syy    = fields + 2  * F;
    float* sxy    = fields + 3  * F;
    float* sxx    = fields + 4  * F;
    float* m_vyy  = fields + 5  * F;
    float* m_vyx  = fields + 6  * F;
    float* m_vxy  = fields + 7  * F;
    float* m_vxx  = fields + 8  * F;
    float* m_syyy = fields + 9  * F;
    float* m_sxyy = fields + 10 * F;
    float* m_sxyx = fields + 11 * F;
    float* m_sxxx = fields + 12 * F;

    init_profiles<<<2, 256, 0, stream>>>(pa, pb);
    halo_zero<<<(5 * NSHOT * NY * 4 + 255) / 256, 256, 0, stream>>>(fields);

    // Cooperative path requires all 1024 blocks resident (>=4 blocks/CU on
    // 256 CUs). Query once; fall back to the verified multi-launch path if
    // the runtime can't guarantee residency.
    static int coop_ok = -1;
    if (coop_ok < 0) {
        int maxb = 0;
        hipError_t e = hipOccupancyMaxActiveBlocksPerMultiprocessor(
            &maxb, reinterpret_cast<const void*>(sim_kernel), 256, 0);
        coop_ok = (e == hipSuccess && maxb >= 4) ? 1 : 0;
    }

    if (coop_ok) {
        void* args[] = {
            (void*)&vy, (void*)&vx, (void*)&syy, (void*)&sxy, (void*)&sxx,
            (void*)&m_syyy, (void*)&m_sxyy, (void*)&m_sxyx, (void*)&m_sxxx,
            (void*)&m_vyy, (void*)&m_vyx, (void*)&m_vxy, (void*)&m_vxx,
            (void*)&buoy, (void*)&lamb, (void*)&mu,
            (void*)&pa, (void*)&pb,
            (void*)&amps, (void*)&srcloc, (void*)&recloc, (void*)&out
        };
        hipLaunchCooperativeKernel(reinterpret_cast<const void*>(sim_kernel),
                                   dim3(1024), dim3(256), args, 0, stream);
    } else {
        dim3 grid(NX / 256, NY, NSHOT);
        dim3 block(256);
        vel_kernel<true><<<grid, block, 0, stream>>>(syy, sxy, sxx, vy, vx,
                                                     m_syyy, m_sxyy, m_sxyx, m_sxxx,
                                                     buoy, pa, pb, amps, srcloc, 0);
        stress_kernel<true><<<grid, block, 0, stream>>>(vy, vx, syy, sxy, sxx,
                                                        m_vyy, m_vyx, m_vxy, m_vxx,
                                                        lamb, mu, pa, pb, recloc, out, 0);
        for (int t = 1; t < NT; ++t) {
            vel_kernel<false><<<grid, block, 0, stream>>>(syy, sxy, sxx, vy, vx,
                                                          m_syyy, m_sxyy, m_sxyx, m_sxxx,
                                                          buoy, pa, pb, amps, srcloc, t);
            stress_kernel<false><<<grid, block, 0, stream>>>(vy, vx, syy, sxy, sxx,
                                                             m_vyy, m_vyx, m_vxy, m_vxx,
                                                             lamb, mu, pa, pb, recloc, out, t);
        }
    }
}